// Round 1
// baseline (164.252 us; speedup 1.0000x reference)
//
#include <hip/hip_runtime.h>

#define NQ 12
#define DIM 4096          // 2^NQ
#define NL 6
#define BATCH 768
#define THREADS 256
#define AMPS_PER_THREAD 16   // DIM / THREADS
#define PAIRS_PER_THREAD 8   // (DIM/2) / THREADS

// One block simulates one batch sample. State vector lives in LDS (32 KB).
// Embedding is a direct product-state init; the CNOT chain per layer is the
// Gray-code permutation new[k] = old[k ^ (k>>1)]; readout mitigation is the
// closed-form pinv of (ones - eye): out_i = (sum_e + n)/(n-1) - e_i - 2.
__global__ __launch_bounds__(THREADS, 4)
void qsim_kernel(const float* __restrict__ x,      // (BATCH, NQ)
                 const float* __restrict__ params, // (NL, NQ, 3)
                 float* __restrict__ out)          // (BATCH, NQ)
{
    __shared__ float2 st[DIM];
    __shared__ float2 gates[NL * NQ * 4];
    __shared__ float cv[NQ], sv[NQ];
    __shared__ float red[4 * NQ];
    __shared__ float ev[NQ];

    const int b = blockIdx.x;
    const int tid = threadIdx.x;

    // ---- gate table: Rot(phi,theta,omega) = RZ(omega) RY(theta) RZ(phi)
    // g00 = e^{-i(phi+omega)/2} cos(t/2), g01 = -e^{i(phi-omega)/2} sin(t/2)
    // g10 = e^{-i(phi-omega)/2} sin(t/2), g11 = e^{ i(phi+omega)/2} cos(t/2)
    if (tid < NL * NQ) {
        const float phi   = params[tid * 3 + 0];
        const float theta = params[tid * 3 + 1];
        const float omega = params[tid * 3 + 2];
        float ct, stt, ca, sa, cb, sb;
        __sincosf(0.5f * theta, &stt, &ct);
        __sincosf(0.5f * (phi + omega), &sa, &ca);
        __sincosf(0.5f * (phi - omega), &sb, &cb);
        float2* g = &gates[tid * 4];
        g[0] = make_float2( ca * ct, -sa * ct);
        g[1] = make_float2(-cb * stt, -sb * stt);
        g[2] = make_float2( cb * stt, -sb * stt);
        g[3] = make_float2( ca * ct,  sa * ct);
    }
    // ---- per-sample embedding angles
    if (tid < NQ) {
        float s, c;
        __sincosf(0.5f * x[b * NQ + tid], &s, &c);
        cv[tid] = c; sv[tid] = s;
    }
    __syncthreads();

    // ---- product-state init: amp(k) = (-i)^pop(k) * prod(bit ? sin : cos)
    {
        float cr[NQ], sr[NQ];
        #pragma unroll
        for (int i = 0; i < NQ; ++i) { cr[i] = cv[i]; sr[i] = sv[i]; }
        #pragma unroll
        for (int j = 0; j < AMPS_PER_THREAD; ++j) {
            const int k = tid + THREADS * j;
            float r = 1.0f;
            #pragma unroll
            for (int i = 0; i < NQ; ++i)
                r *= ((k >> (NQ - 1 - i)) & 1) ? sr[i] : cr[i];
            const int pop = __popc(k) & 3;
            float2 a;
            if      (pop == 0) a = make_float2( r, 0.0f);
            else if (pop == 1) a = make_float2(0.0f, -r);
            else if (pop == 2) a = make_float2(-r, 0.0f);
            else               a = make_float2(0.0f,  r);
            st[k] = a;
        }
    }
    __syncthreads();

    // ---- variational layers
    for (int l = 0; l < NL; ++l) {
        for (int q = 0; q < NQ; ++q) {
            const float2 g00 = gates[(l * NQ + q) * 4 + 0];
            const float2 g01 = gates[(l * NQ + q) * 4 + 1];
            const float2 g10 = gates[(l * NQ + q) * 4 + 2];
            const float2 g11 = gates[(l * NQ + q) * 4 + 3];
            const int s = 1 << (NQ - 1 - q);
            #pragma unroll
            for (int jj = 0; jj < PAIRS_PER_THREAD; ++jj) {
                const int p = tid + THREADS * jj;
                const int k0 = ((p & ~(s - 1)) << 1) | (p & (s - 1));
                const int k1 = k0 + s;
                const float2 a0 = st[k0];
                const float2 a1 = st[k1];
                float2 n0, n1;
                n0.x = g00.x * a0.x - g00.y * a0.y + g01.x * a1.x - g01.y * a1.y;
                n0.y = g00.x * a0.y + g00.y * a0.x + g01.x * a1.y + g01.y * a1.x;
                n1.x = g10.x * a0.x - g10.y * a0.y + g11.x * a1.x - g11.y * a1.y;
                n1.y = g10.x * a0.y + g10.y * a0.x + g11.x * a1.y + g11.y * a1.x;
                st[k0] = n0;
                st[k1] = n1;
            }
            __syncthreads();
        }
        // CNOT chain q->q+1, q=0..10  ==  new[k] = old[gray(k)], gray(k)=k^(k>>1)
        float2 regs[AMPS_PER_THREAD];
        #pragma unroll
        for (int j = 0; j < AMPS_PER_THREAD; ++j) {
            const int k = tid + THREADS * j;
            regs[j] = st[k ^ (k >> 1)];
        }
        __syncthreads();
        #pragma unroll
        for (int j = 0; j < AMPS_PER_THREAD; ++j) {
            const int k = tid + THREADS * j;
            st[k] = regs[j];
        }
        __syncthreads();
    }

    // ---- <Z_i> partials from this thread's 16 amplitudes
    float part[NQ];
    #pragma unroll
    for (int i = 0; i < NQ; ++i) part[i] = 0.0f;
    #pragma unroll
    for (int j = 0; j < AMPS_PER_THREAD; ++j) {
        const int k = tid + THREADS * j;
        const float2 a = st[k];
        const float p = a.x * a.x + a.y * a.y;
        #pragma unroll
        for (int i = 0; i < NQ; ++i)
            part[i] += ((k >> (NQ - 1 - i)) & 1) ? -p : p;
    }
    // wave (64-lane) butterfly reduction
    #pragma unroll
    for (int i = 0; i < NQ; ++i) {
        #pragma unroll
        for (int off = 32; off > 0; off >>= 1)
            part[i] += __shfl_xor(part[i], off);
    }
    const int wave = tid >> 6;
    if ((tid & 63) == 0) {
        #pragma unroll
        for (int i = 0; i < NQ; ++i) red[wave * NQ + i] = part[i];
    }
    __syncthreads();
    if (tid < NQ) {
        ev[tid] = red[tid] + red[NQ + tid] + red[2 * NQ + tid] + red[3 * NQ + tid];
    }
    __syncthreads();
    // ---- readout mitigation, closed form: out_i = (S + n)/(n-1) - e_i - 2
    if (tid < NQ) {
        float S = 0.0f;
        #pragma unroll
        for (int i = 0; i < NQ; ++i) S += ev[i];
        out[b * NQ + tid] = (S + 12.0f) * (1.0f / 11.0f) - ev[tid] - 2.0f;
    }
}

extern "C" void kernel_launch(void* const* d_in, const int* in_sizes, int n_in,
                              void* d_out, int out_size, void* d_ws, size_t ws_size,
                              hipStream_t stream) {
    const float* x      = (const float*)d_in[0];
    const float* params = (const float*)d_in[1];
    float* out = (float*)d_out;
    qsim_kernel<<<dim3(BATCH), dim3(THREADS), 0, stream>>>(x, params, out);
}

// Round 2
// 156.023 us; speedup vs baseline: 1.0527x; 1.0527x over previous
//
#include <hip/hip_runtime.h>

#define NQ 12
#define DIM 4096
#define NL 6
#define THREADS 256
#define BATCH 768

// ---------------- compile-time GF(2) Gray-frame tables ----------------
// After l CNOT-chain layers the logical->stored index map is A_l = G^l where
// G(k) = k ^ (k>>1) (linear over GF(2)^12). A gate on logical qubit q (bit
// p = 11-q) acts on stored pairs {s, s^M} with M = G^l e_p (column of A_l),
// and the |0>-side is the s with parity(F & s) == 0, F = row p of G^-l.
// parity(F & M) == 1 always (it's (A^-1 A)_pp), so every pair is well-formed.
constexpr unsigned grayl(unsigned v, int l) {
    for (int i = 0; i < l; ++i) v ^= (v >> 1);
    return v & 0xFFFu;
}
constexpr unsigned ungray1(unsigned v) {
    v ^= v >> 1; v ^= v >> 2; v ^= v >> 4; v ^= v >> 8;
    return v & 0xFFFu;
}
constexpr unsigned ungrayl(unsigned v, int l) {
    for (int i = 0; i < l; ++i) v = ungray1(v);
    return v & 0xFFFu;
}
constexpr unsigned frow(int p, int l) {
    unsigned f = 0;
    for (int b = 0; b < 12; ++b)
        if ((ungrayl(1u << b, l) >> p) & 1) f |= 1u << b;
    return f;
}
struct FQT { unsigned v[NQ]; };
constexpr FQT make_fq() {
    FQT t{};
    for (int q = 0; q < NQ; ++q) t.v[q] = frow(11 - q, NL);
    return t;
}
constexpr FQT FQTAB = make_fq();

__device__ __forceinline__ float2 cmul2(float2 c0, float2 a, float2 c1, float2 b) {
    float2 r;
    r.x = c0.x * a.x - c0.y * a.y + c1.x * b.x - c1.y * b.y;
    r.y = c0.x * a.y + c0.y * a.x + c1.x * b.y + c1.y * b.x;
    return r;
}

// One gate pass: layer L (0-based), qubit Q. State layout: stored index
// sigma = (tid<<4) | j ; j = per-thread register index (bits 3..0),
// tid bits 5..0 = lane (sigma bits 9..4), tid bits 7..6 = wave (bits 11..10).
template<int L, int Q>
__device__ __forceinline__ void pass(float2 (&amp)[16], const float2* __restrict__ gc,
                                     float2* __restrict__ st, const int tid) {
    constexpr int P = 11 - Q;
    constexpr unsigned M   = grayl(1u << P, L);
    constexpr unsigned F   = frow(P, L);
    constexpr unsigned MLO = M & 15u;
    constexpr unsigned MHI = M >> 4;
    constexpr unsigned FLO = F & 15u;
    constexpr unsigned FHI = F >> 4;

    const float2* g = gc + (L * NQ + Q) * 4;
    const float2 q00 = g[0], q01 = g[1], q10 = g[2], q11 = g[3];
    // thread-level role parity; orient the gate so that register-level parity
    // (compile-time per j) selects the correct row.
    const bool ph = (__popc(FHI & (unsigned)tid) & 1) != 0;
    const float2 a00 = ph ? q11 : q00;
    const float2 a01 = ph ? q10 : q01;
    const float2 a10 = ph ? q01 : q10;
    const float2 a11 = ph ? q00 : q11;

    if constexpr (MHI >= 64u) {
        // ---- cross-wave pass via XOR-swizzled LDS round trip ----
        __syncthreads();   // WAR: previous LDS pass's reads must be done
        const unsigned wbase = (unsigned)tid * 16u;
        const unsigned ws = (unsigned)tid & 15u;
        #pragma unroll
        for (int j = 0; j < 16; ++j) st[wbase + ((unsigned)j ^ ws)] = amp[j];
        __syncthreads();
        const unsigned tp = (unsigned)tid ^ MHI;
        const unsigned rbase = tp * 16u;
        const unsigned rs = tp & 15u;
        float2 pv[16];
        #pragma unroll
        for (int j = 0; j < 16; ++j) pv[j] = st[rbase + (((unsigned)j ^ MLO) ^ rs)];
        #pragma unroll
        for (int j = 0; j < 16; ++j) {
            if ((__builtin_popcount(FLO & (unsigned)j) & 1) == 0)
                amp[j] = cmul2(a00, amp[j], a01, pv[j]);
            else
                amp[j] = cmul2(a11, amp[j], a10, pv[j]);
        }
    } else if constexpr (MHI != 0u) {
        // ---- cross-lane pass via shuffle ----
        float2 pv[16];
        #pragma unroll
        for (int j = 0; j < 16; ++j) {
            const float2 src = amp[j ^ (int)MLO];
            pv[j].x = __shfl_xor(src.x, (int)MHI, 64);
            pv[j].y = __shfl_xor(src.y, (int)MHI, 64);
        }
        #pragma unroll
        for (int j = 0; j < 16; ++j) {
            if ((__builtin_popcount(FLO & (unsigned)j) & 1) == 0)
                amp[j] = cmul2(a00, amp[j], a01, pv[j]);
            else
                amp[j] = cmul2(a11, amp[j], a10, pv[j]);
        }
    } else {
        // ---- pure register pass ----
        #pragma unroll
        for (int j = 0; j < 16; ++j) {
            if ((__builtin_popcount(FLO & (unsigned)j) & 1) == 0) {
                const int jb = j ^ (int)MLO;
                const float2 a = amp[j], b = amp[jb];
                amp[j]  = cmul2(a00, a, a01, b);
                amp[jb] = cmul2(a10, a, a11, b);
            }
        }
    }
}

template<int L>
__device__ __forceinline__ void layer(float2 (&amp)[16], const float2* __restrict__ gc,
                                      float2* __restrict__ st, const int tid) {
    // gates within a layer commute (distinct qubits) — do register/lane first,
    // cross-wave (q=0,1) last.
    pass<L, 11>(amp, gc, st, tid);
    pass<L, 10>(amp, gc, st, tid);
    pass<L,  9>(amp, gc, st, tid);
    pass<L,  8>(amp, gc, st, tid);
    pass<L,  7>(amp, gc, st, tid);
    pass<L,  6>(amp, gc, st, tid);
    pass<L,  5>(amp, gc, st, tid);
    pass<L,  4>(amp, gc, st, tid);
    pass<L,  3>(amp, gc, st, tid);
    pass<L,  2>(amp, gc, st, tid);
    pass<L,  1>(amp, gc, st, tid);
    pass<L,  0>(amp, gc, st, tid);
}

__global__ __launch_bounds__(THREADS)
void qsim_kernel(const float* __restrict__ x,      // (BATCH, NQ)
                 const float* __restrict__ params, // (NL, NQ, 3)
                 float* __restrict__ out)          // (BATCH, NQ)
{
    __shared__ float2 st[DIM];            // 32 KB cross-wave exchange buffer
    __shared__ float2 gates[NL * NQ * 4]; // 4.6 KB
    __shared__ float cv[NQ], sv[NQ];
    __shared__ float red[4 * NQ];
    __shared__ float ev[NQ];

    const int b = blockIdx.x;
    const int tid = threadIdx.x;

    // ---- gate table (batch-invariant): Rot = RZ(omega) RY(theta) RZ(phi)
    if (tid < NL * NQ) {
        const float phi   = params[tid * 3 + 0];
        const float theta = params[tid * 3 + 1];
        const float omega = params[tid * 3 + 2];
        float ct, stt, ca, sa, cb, sb;
        __sincosf(0.5f * theta, &stt, &ct);
        __sincosf(0.5f * (phi + omega), &sa, &ca);
        __sincosf(0.5f * (phi - omega), &sb, &cb);
        float2* g = &gates[tid * 4];
        g[0] = make_float2( ca * ct, -sa * ct);
        g[1] = make_float2(-cb * stt, -sb * stt);
        g[2] = make_float2( cb * stt, -sb * stt);
        g[3] = make_float2( ca * ct,  sa * ct);
    }
    // ---- per-sample embedding angles (on a different wave than gate build)
    if (tid >= 128 && tid < 128 + NQ) {
        const int i = tid - 128;
        float s, c;
        __sincosf(0.5f * x[b * NQ + i], &s, &c);
        cv[i] = c; sv[i] = s;
    }
    __syncthreads();

    // ---- product-state init directly into registers
    // qubit i <-> sigma bit (11-i); sigma = (tid<<4)|j
    float rhi = 1.0f;
    #pragma unroll
    for (int i = 0; i < 8; ++i) rhi *= ((tid >> (7 - i)) & 1) ? sv[i] : cv[i];
    const int pt = __popc(tid);

    float2 amp[16];
    #pragma unroll
    for (int j = 0; j < 16; ++j) {
        float v = rhi;
        #pragma unroll
        for (int i = 8; i < 12; ++i) v *= ((j >> (11 - i)) & 1) ? sv[i] : cv[i];
        const int phj = (pt + __builtin_popcount((unsigned)j)) & 3;
        amp[j].x = (phj == 0) ? v : (phj == 2) ? -v : 0.0f;
        amp[j].y = (phj == 1) ? -v : (phj == 3) ? v : 0.0f;
    }

    // ---- 6 variational layers, CNOT chains folded into the GF(2) frame
    layer<0>(amp, gates, st, tid);
    layer<1>(amp, gates, st, tid);
    layer<2>(amp, gates, st, tid);
    layer<3>(amp, gates, st, tid);
    layer<4>(amp, gates, st, tid);
    layer<5>(amp, gates, st, tid);

    // ---- <Z_q> with frame-adjusted sign functionals FQ = rows of G^-6
    float p[16];
    #pragma unroll
    for (int j = 0; j < 16; ++j)
        p[j] = amp[j].x * amp[j].x + amp[j].y * amp[j].y;

    float part[NQ];
    #pragma unroll
    for (int q = 0; q < NQ; ++q) {
        constexpr unsigned dummy = 0; (void)dummy;
        const unsigned fq = FQTAB.v[q];
        float acc = 0.0f;
        #pragma unroll
        for (int j = 0; j < 16; ++j) {
            if (__builtin_popcount(fq & 15u & (unsigned)j) & 1) acc -= p[j];
            else                                                acc += p[j];
        }
        part[q] = (__popc((fq >> 4) & (unsigned)tid) & 1) ? -acc : acc;
    }

    // ---- wave butterfly + block reduction
    #pragma unroll
    for (int q = 0; q < NQ; ++q) {
        #pragma unroll
        for (int off = 32; off > 0; off >>= 1)
            part[q] += __shfl_xor(part[q], off, 64);
    }
    const int wave = tid >> 6;
    if ((tid & 63) == 0) {
        #pragma unroll
        for (int q = 0; q < NQ; ++q) red[wave * NQ + q] = part[q];
    }
    __syncthreads();
    if (tid < NQ)
        ev[tid] = red[tid] + red[NQ + tid] + red[2 * NQ + tid] + red[3 * NQ + tid];
    __syncthreads();
    // ---- readout mitigation, closed-form pinv: out_i = (S+n)/(n-1) - e_i - 2
    if (tid < NQ) {
        float S = 0.0f;
        #pragma unroll
        for (int i = 0; i < NQ; ++i) S += ev[i];
        out[b * NQ + tid] = (S + 12.0f) * (1.0f / 11.0f) - ev[tid] - 2.0f;
    }
}

extern "C" void kernel_launch(void* const* d_in, const int* in_sizes, int n_in,
                              void* d_out, int out_size, void* d_ws, size_t ws_size,
                              hipStream_t stream) {
    const float* x      = (const float*)d_in[0];
    const float* params = (const float*)d_in[1];
    float* out = (float*)d_out;
    qsim_kernel<<<dim3(BATCH), dim3(THREADS), 0, stream>>>(x, params, out);
}

// Round 4
// 103.832 us; speedup vs baseline: 1.5819x; 1.5026x over previous
//
#include <hip/hip_runtime.h>

#define NQ 12
#define DIM 4096
#define NL 6
#define THREADS 512
#define BATCH 768
#define AMPS 8

// ---------------- compile-time GF(2) machinery ----------------
// Frame: after l CNOT-chain layers, logical index k relates to stored sigma by
// sigma = G^l k (G(v) = v ^ (v>>1)). We KEEP the state in logical coords of the
// current frame: layout sigma = G^L * c, where c = (tid<<3)|j. Then every gate
// of layer L acts on c-bit p (p = 11 - qubit), role = bit value. Two LDS
// transits per layer: T (swap c[11:9]<->c[2:0]) to make the wave-bit gates
// register-local, then c' = G^{-1} T c to enter the next layer's frame.
constexpr unsigned grayl(unsigned v, int l) {
    for (int i = 0; i < l; ++i) v ^= (v >> 1);
    return v & 0xFFFu;
}
constexpr unsigned ungray1(unsigned v) {
    v ^= v >> 1; v ^= v >> 2; v ^= v >> 4; v ^= v >> 8;
    return v & 0xFFFu;
}
constexpr unsigned ungrayl(unsigned v, int l) {
    for (int i = 0; i < l; ++i) v = ungray1(v);
    return v & 0xFFFu;
}
constexpr unsigned frow(int p, int l) {   // row p of G^{-l}
    unsigned f = 0;
    for (int b = 0; b < 12; ++b)
        if ((ungrayl(1u << b, l) >> p) & 1) f |= 1u << b;
    return f;
}
constexpr unsigned Tsw(unsigned v) {      // swap bits (11,2),(10,1),(9,0)
    unsigned d = ((v >> 9) ^ v) & 7u;
    return v ^ (d << 9) ^ d;
}
constexpr int par12(unsigned v) { int c = 0; for (int b = 0; b < 12; ++b) c ^= (v >> b) & 1; return c; }
// Readout functional for qubit q on final c (layout G^5 * T):
// sign bit = parity(RQ[q] & c), RQ[q]_b = parity(frow(11-q,6) & G^5 T e_b)
constexpr unsigned rqf(int q) {
    unsigned F = frow(11 - q, NL);
    unsigned r = 0;
    for (int b = 0; b < 12; ++b)
        if (par12(F & grayl(Tsw(1u << b), NL - 1))) r |= 1u << b;
    return r;
}
struct RQT { unsigned v[NQ]; };
constexpr RQT make_rq() { RQT t{}; for (int q = 0; q < NQ; ++q) t.v[q] = rqf(q); return t; }
constexpr RQT RQTAB = make_rq();

// ---------------- device helpers ----------------
__device__ __forceinline__ float2 crow(float2 c0, float2 a, float2 c1, float2 b) {
    float2 r;
    r.x = c0.x * a.x - c0.y * a.y + c1.x * b.x - c1.y * b.y;
    r.y = c0.x * a.y + c0.y * a.x + c1.x * b.y + c1.y * b.x;
    return r;
}
template<int CTRL>
__device__ __forceinline__ float2 dppx(float2 v) {   // quad_perm lane exchange
    float2 r;
    r.x = __int_as_float(__builtin_amdgcn_update_dpp(0, __float_as_int(v.x), CTRL, 0xF, 0xF, true));
    r.y = __int_as_float(__builtin_amdgcn_update_dpp(0, __float_as_int(v.y), CTRL, 0xF, 0xF, true));
    return r;
}
template<int XM>
__device__ __forceinline__ float2 swzx(float2 v) {   // ds_swizzle xor-mask (XM<32)
    float2 r;
    r.x = __int_as_float(__builtin_amdgcn_ds_swizzle(__float_as_int(v.x), (XM << 10) | 0x1F));
    r.y = __int_as_float(__builtin_amdgcn_ds_swizzle(__float_as_int(v.y), (XM << 10) | 0x1F));
    return r;
}
template<int XM>
__device__ __forceinline__ float2 lexch(float2 v) {
    if constexpr (XM == 1)  return dppx<0xB1>(v);          // quad_perm [1,0,3,2]
    else if constexpr (XM == 2) return dppx<0x4E>(v);      // quad_perm [2,3,0,1]
    else if constexpr (XM == 32) {
        float2 r; r.x = __shfl_xor(v.x, 32, 64); r.y = __shfl_xor(v.y, 32, 64); return r;
    } else return swzx<XM>(v);
}

// gate on register bit RB: pairs (j, j|1<<RB), |0>-side = bit clear
template<int RB>
__device__ __forceinline__ void regpass(float2 (&amp)[AMPS], const float2* __restrict__ g) {
    const float2 g00 = g[0], g01 = g[1], g10 = g[2], g11 = g[3];
    #pragma unroll
    for (int j = 0; j < AMPS; ++j)
        if (!(j & (1 << RB))) {
            const int jb = j | (1 << RB);
            const float2 a = amp[j], b = amp[jb];
            amp[j]  = crow(g00, a, g01, b);
            amp[jb] = crow(g10, a, g11, b);
        }
}
// gate on lane bit (xor mask XM): role = lane&XM
template<int XM>
__device__ __forceinline__ void lanepass(float2 (&amp)[AMPS], const float2* __restrict__ g, int lane) {
    const float2 q00 = g[0], q01 = g[1], q10 = g[2], q11 = g[3];
    const bool ph = (lane & XM) != 0;
    const float2 a00 = ph ? q11 : q00;
    const float2 a01 = ph ? q10 : q01;
    #pragma unroll
    for (int j = 0; j < AMPS; ++j) {
        const float2 pv = lexch<XM>(amp[j]);
        amp[j] = crow(a00, amp[j], a01, pv);
    }
}

template<int L>
__device__ __forceinline__ void layer(float2 (&amp)[AMPS], const float2* __restrict__ gates,
                                      float2* __restrict__ st, const int tid, const int lane,
                                      const int t1base, const unsigned RA) {
    const float2* G = gates + L * NQ * 4;
    // qubits 11..9 -> reg bits 0..2 ; qubits 8..3 -> lane xor 1..32
    regpass<0>(amp, G + 11 * 4);
    regpass<1>(amp, G + 10 * 4);
    regpass<2>(amp, G +  9 * 4);
    lanepass<1>(amp, G + 8 * 4, lane);
    lanepass<2>(amp, G + 7 * 4, lane);
    lanepass<4>(amp, G + 6 * 4, lane);
    lanepass<8>(amp, G + 5 * 4, lane);
    lanepass<16>(amp, G + 4 * 4, lane);
    lanepass<32>(amp, G + 3 * 4, lane);
    // ---- transit 1: layout G^L -> G^L*T  (cell index = holder coords (j<<9)|tid)
    __syncthreads();
    #pragma unroll
    for (int j = 0; j < AMPS; ++j) st[(j << 9) | tid] = amp[j];
    __syncthreads();
    #pragma unroll
    for (int j = 0; j < AMPS; ++j) amp[j] = st[t1base + (j << 6)];
    // qubits 0,1,2 now on reg bits 2,1,0
    regpass<2>(amp, G + 0 * 4);
    regpass<1>(amp, G + 1 * 4);
    regpass<0>(amp, G + 2 * 4);
    if constexpr (L < NL - 1) {
        // ---- transit 2: layout G^L*T -> G^{L+1}; c_old = T(G c_new)
        __syncthreads();
        #pragma unroll
        for (int j = 0; j < AMPS; ++j) st[(j << 9) | tid] = amp[j];
        __syncthreads();
        #pragma unroll
        for (int j = 0; j < AMPS; ++j)
            amp[j] = st[RA ^ (unsigned)(((j ^ (j >> 1)) << 6))];
    }
}

__global__ __launch_bounds__(THREADS, 6)
void qsim_kernel(const float* __restrict__ x,      // (BATCH, NQ)
                 const float* __restrict__ params, // (NL, NQ, 3)
                 float* __restrict__ out)          // (BATCH, NQ)
{
    __shared__ float2 st[DIM];            // 32 KB transit buffer
    __shared__ float2 gates[NL * NQ * 4]; // 2.25 KB
    __shared__ float cv[NQ], sv[NQ];
    __shared__ float red[8 * NQ];
    __shared__ float ev[NQ];

    const int b = blockIdx.x;
    const int tid = threadIdx.x;
    const int lane = tid & 63;
    const int wave = tid >> 6;
    const int t1base = (wave << 9) | lane;

    // transit-2 read base: c_old = T(G c), addr = ror3(Tsw(H)), H = G-part from tid
    const unsigned u = (unsigned)((tid ^ (tid >> 1)) & 0x1FF);
    const unsigned H = (u << 3) ^ (((unsigned)tid & 1u) << 2);
    const unsigned d = ((H >> 9) ^ H) & 7u;
    const unsigned Ht = H ^ (d << 9) ^ d;
    const unsigned RA = ((Ht >> 3) | (Ht << 9)) & 0xFFFu;

    // ---- gate table (batch-invariant): Rot = RZ(omega) RY(theta) RZ(phi)
    if (tid < NL * NQ) {
        const float phi   = params[tid * 3 + 0];
        const float theta = params[tid * 3 + 1];
        const float omega = params[tid * 3 + 2];
        float ct, stt, ca, sa, cb, sb;
        __sincosf(0.5f * theta, &stt, &ct);
        __sincosf(0.5f * (phi + omega), &sa, &ca);
        __sincosf(0.5f * (phi - omega), &sb, &cb);
        float2* g = &gates[tid * 4];
        g[0] = make_float2( ca * ct, -sa * ct);
        g[1] = make_float2(-cb * stt, -sb * stt);
        g[2] = make_float2( cb * stt, -sb * stt);
        g[3] = make_float2( ca * ct,  sa * ct);
    }
    if (tid >= 128 && tid < 128 + NQ) {
        const int i = tid - 128;
        float s, c;
        __sincosf(0.5f * x[b * NQ + i], &s, &c);
        cv[i] = c; sv[i] = s;
    }
    __syncthreads();

    // ---- product-state init in c = sigma coords (frame 0):
    // qubit i<->c-bit 11-i: i=0..8 -> tid bit 8-i; i=9,10,11 -> j bits 2,1,0
    float rt = 1.0f;
    #pragma unroll
    for (int i = 0; i < 9; ++i) rt *= ((tid >> (8 - i)) & 1) ? sv[i] : cv[i];
    const int pt = __popc((unsigned)tid & 0x1FFu);

    float2 amp[AMPS];
    #pragma unroll
    for (int j = 0; j < AMPS; ++j) {
        float v = rt;
        v *= (j & 4) ? sv[9]  : cv[9];
        v *= (j & 2) ? sv[10] : cv[10];
        v *= (j & 1) ? sv[11] : cv[11];
        const int phj = (pt + __builtin_popcount((unsigned)j)) & 3;
        amp[j].x = (phj == 0) ? v : (phj == 2) ? -v : 0.0f;
        amp[j].y = (phj == 1) ? -v : (phj == 3) ? v : 0.0f;
    }

    // ---- 6 layers
    layer<0>(amp, gates, st, tid, lane, t1base, RA);
    layer<1>(amp, gates, st, tid, lane, t1base, RA);
    layer<2>(amp, gates, st, tid, lane, t1base, RA);
    layer<3>(amp, gates, st, tid, lane, t1base, RA);
    layer<4>(amp, gates, st, tid, lane, t1base, RA);
    layer<5>(amp, gates, st, tid, lane, t1base, RA);

    // ---- <Z_q> via constexpr functionals on final layout (G^5 * T)
    float p[AMPS];
    #pragma unroll
    for (int j = 0; j < AMPS; ++j)
        p[j] = amp[j].x * amp[j].x + amp[j].y * amp[j].y;

    float part[NQ];
    #pragma unroll
    for (int q = 0; q < NQ; ++q) {
        const unsigned rv = RQTAB.v[q];
        float acc = 0.0f;
        #pragma unroll
        for (int j = 0; j < AMPS; ++j) {
            if (__builtin_popcount(rv & 7u & (unsigned)j) & 1) acc -= p[j];
            else                                               acc += p[j];
        }
        part[q] = (__popc((rv >> 3) & (unsigned)tid) & 1) ? -acc : acc;
    }
    #pragma unroll
    for (int q = 0; q < NQ; ++q) {
        #pragma unroll
        for (int off = 32; off > 0; off >>= 1)
            part[q] += __shfl_xor(part[q], off, 64);
    }
    if (lane == 0) {
        #pragma unroll
        for (int q = 0; q < NQ; ++q) red[wave * NQ + q] = part[q];
    }
    __syncthreads();
    if (tid < NQ) {
        float e = 0.0f;
        #pragma unroll
        for (int w = 0; w < 8; ++w) e += red[w * NQ + tid];
        ev[tid] = e;
    }
    __syncthreads();
    // readout mitigation, closed-form pinv: out_i = (S+n)/(n-1) - e_i - 2
    if (tid < NQ) {
        float S = 0.0f;
        #pragma unroll
        for (int i = 0; i < NQ; ++i) S += ev[i];
        out[b * NQ + tid] = (S + 12.0f) * (1.0f / 11.0f) - ev[tid] - 2.0f;
    }
}

extern "C" void kernel_launch(void* const* d_in, const int* in_sizes, int n_in,
                              void* d_out, int out_size, void* d_ws, size_t ws_size,
                              hipStream_t stream) {
    const float* x      = (const float*)d_in[0];
    const float* params = (const float*)d_in[1];
    float* out = (float*)d_out;
    qsim_kernel<<<dim3(BATCH), dim3(THREADS), 0, stream>>>(x, params, out);
}